// Round 1
// baseline (2805.177 us; speedup 1.0000x reference)
//
#include <hip/hip_runtime.h>
#include <math.h>

// ---------------- compile-time sizes ----------------
namespace {
constexpr int B_ = 8, T_ = 128, D_ = 512, C_ = 1000, L_ = 8, U_ = 16, E_ = 256, H_ = 4;
constexpr int DH_ = D_ / H_;      // 128
constexpr int E4_ = 4 * E_;       // 1024
constexpr int D4_ = 4 * D_;       // 2048
constexpr int TU_ = T_ * U_;      // 2048
constexpr int HC_ = H_ * C_;      // 4000
constexpr float SCALE_ = 0.088388347648318447f; // 1/sqrt(128)

// ---------------- ws layout (float offsets) ----------------
constexpr size_t Z_CTX  = 0;                                  // 2*C*4E
constexpr size_t H_F    = Z_CTX + 2ul * C_ * E4_;
constexpr size_t C_F    = H_F  + (size_t)C_ * E_;
constexpr size_t H_Bo   = C_F  + (size_t)C_ * E_;
constexpr size_t C_Bo   = H_Bo + (size_t)C_ * E_;
constexpr size_t HIST_C = C_Bo + (size_t)C_ * E_;             // B*D
constexpr size_t HF_ALL = HIST_C + (size_t)B_ * D_;
constexpr size_t HB_ALL = HF_ALL + (size_t)C_ * L_ * E_;
constexpr size_t CATM   = HB_ALL + (size_t)C_ * L_ * E_;      // C*2E
constexpr size_t CTXM   = CATM + (size_t)C_ * 2 * E_;         // C*D
constexpr size_t K_WS   = CTXM + (size_t)C_ * D_;
constexpr size_t V_WS   = K_WS + (size_t)C_ * D_;
constexpr size_t HXP    = V_WS + (size_t)C_ * D_;             // B*U*4D
constexpr size_t HALL   = HXP + (size_t)B_ * U_ * D4_;        // B*U*D
constexpr size_t HPROJ  = HALL + (size_t)B_ * U_ * D_;
constexpr size_t MP_    = HPROJ + (size_t)B_ * U_ * D_;       // B*T*D
constexpr size_t QM_    = MP_ + (size_t)B_ * T_ * D_;
constexpr size_t QH_    = QM_ + (size_t)B_ * T_ * D_;         // B*U*D
constexpr size_t SM_    = QH_ + (size_t)B_ * U_ * D_;         // B*T*H*C
constexpr size_t SH_    = SM_ + (size_t)B_ * T_ * HC_;        // B*U*H*C
constexpr size_t STATS_ = SH_ + (size_t)B_ * U_ * HC_;        // float2 * B*T*U*H
constexpr size_t AOUT_  = STATS_ + 2ul * B_ * T_ * U_ * H_;   // B*TU*D
constexpr size_t OFIN_  = AOUT_ + (size_t)B_ * TU_ * D_;      // B*TU*D
constexpr size_t BITS_  = OFIN_ + (size_t)B_ * TU_ * D_;      // 16384 bytes = 4096 floats
constexpr size_t USEL_  = BITS_ + 4096;                       // B*T ints
constexpr size_t WS_NEED = USEL_ + (size_t)B_ * T_;
} // namespace

// ---------------- generic NT GEMM (X @ W^T), 64x64 tile ----------------
struct GemmP {
  const float* A1; int lda1;
  const int* ridx; int ridx_stride; int ridx_off;  // optional row gather on A1
  const float* A2; int lda2;                       // optional K-concat source
  int K1, K2;
  const float* W1; int ldw1;
  const float* W2; int ldw2;
  const float* bias;                               // optional len-N
  float* out; int ldc;
  int M, N;
  float scale;
  int a_zoff, w_zoff, c_zoff;                      // per-blockIdx.z pointer offsets
};

__device__ __forceinline__ void gemm_core(const GemmP& g, int z) {
  __shared__ float As[16][68];
  __shared__ float Ws[16][68];
  const float* A1 = g.A1 + (long)z * g.a_zoff;
  const float* W1 = g.W1 + (long)z * g.w_zoff;
  float* out = g.out + (long)z * g.c_zoff;
  const int m0 = blockIdx.y * 64;
  const int n0 = blockIdx.x * 64;
  const int tid = threadIdx.x;
  const int tx = tid & 15, ty = tid >> 4;
  const int lk = tid & 15, lr0 = tid >> 4;
  float acc[4][4] = {};
  const int K = g.K1 + g.K2;
  for (int k0 = 0; k0 < K; k0 += 16) {
    const int kk = k0 + lk;
    const bool inK1 = kk < g.K1;
#pragma unroll
    for (int p = 0; p < 4; ++p) {
      const int r = lr0 + p * 16;
      const int gm = m0 + r;
      float vA = 0.f;
      if (gm < g.M) {
        if (inK1) {
          const int ar = g.ridx ? g.ridx[gm * g.ridx_stride + g.ridx_off] : gm;
          vA = A1[(long)ar * g.lda1 + kk];
        } else {
          vA = g.A2[(long)gm * g.lda2 + (kk - g.K1)];
        }
      }
      As[lk][r] = vA;
      const int gn = n0 + r;
      float vW = 0.f;
      if (gn < g.N) {
        vW = inK1 ? W1[(long)gn * g.ldw1 + kk]
                  : g.W2[(long)gn * g.ldw2 + (kk - g.K1)];
      }
      Ws[lk][r] = vW;
    }
    __syncthreads();
#pragma unroll
    for (int k = 0; k < 16; ++k) {
      const float4 a = *(const float4*)&As[k][ty * 4];
      const float4 w = *(const float4*)&Ws[k][tx * 4];
      acc[0][0] += a.x * w.x; acc[0][1] += a.x * w.y; acc[0][2] += a.x * w.z; acc[0][3] += a.x * w.w;
      acc[1][0] += a.y * w.x; acc[1][1] += a.y * w.y; acc[1][2] += a.y * w.z; acc[1][3] += a.y * w.w;
      acc[2][0] += a.z * w.x; acc[2][1] += a.z * w.y; acc[2][2] += a.z * w.z; acc[2][3] += a.z * w.w;
      acc[3][0] += a.w * w.x; acc[3][1] += a.w * w.y; acc[3][2] += a.w * w.z; acc[3][3] += a.w * w.w;
    }
    __syncthreads();
  }
#pragma unroll
  for (int i = 0; i < 4; ++i) {
    const int gm = m0 + ty * 4 + i;
    if (gm >= g.M) continue;
#pragma unroll
    for (int j = 0; j < 4; ++j) {
      const int gn = n0 + tx * 4 + j;
      if (gn >= g.N) continue;
      float v = acc[i][j];
      if (g.bias) v += g.bias[gn];
      out[(long)gm * g.ldc + gn] = v * g.scale;
    }
  }
}

__global__ __launch_bounds__(256) void k_gemm(GemmP p) { gemm_core(p, blockIdx.z); }
__global__ __launch_bounds__(256) void k_gemm2(GemmP p0, GemmP p1) {
  if (blockIdx.z) gemm_core(p1, 0); else gemm_core(p0, 0);
}

// ---------------- ctx LSTM gates (both directions) ----------------
__global__ __launch_bounds__(256) void k_ctx_gates(
    const float* __restrict__ z_ws,
    float* __restrict__ h_f, float* __restrict__ c_f,
    float* __restrict__ h_b, float* __restrict__ c_b,
    float* __restrict__ hf_all, float* __restrict__ hb_all, int t) {
  int idx = blockIdx.x * 256 + threadIdx.x;
  if (idx >= C_ * E_) return;
  int dir = blockIdx.y;
  int c = idx / E_, e = idx - c * E_;
  const float* z = z_ws + (size_t)dir * C_ * E4_ + (size_t)c * E4_;
  float zi = z[e], zf = z[e + E_], zg = z[e + 2 * E_], zo = z[e + 3 * E_];
  float* cs = dir ? c_b : c_f;
  float* hs = dir ? h_b : h_f;
  float ig = 1.f / (1.f + expf(-zi));
  float fg = 1.f / (1.f + expf(-zf));
  float gg = tanhf(zg);
  float og = 1.f / (1.f + expf(-zo));
  float cn = fg * cs[idx] + ig * gg;
  float hn = og * tanhf(cn);
  cs[idx] = cn; hs[idx] = hn;
  int lpos = dir ? (L_ - 1 - t) : t;
  (dir ? hb_all : hf_all)[((size_t)c * L_ + lpos) * E_ + e] = hn;
}

// ---------------- masked mean over L of concat(hf,hb) ----------------
__global__ __launch_bounds__(256) void k_ctx_mean(
    const float* __restrict__ hf_all, const float* __restrict__ hb_all,
    const int* __restrict__ ilens, float* __restrict__ cat_mean) {
  int idx = blockIdx.x * 256 + threadIdx.x;
  if (idx >= C_ * 2 * E_) return;
  int c = idx / (2 * E_), e = idx - c * 2 * E_;
  const float* src = (e < E_) ? hf_all : hb_all;
  int ee = e & (E_ - 1);
  int il = ilens[c];
  float s = 0.f;
#pragma unroll
  for (int l = 0; l < L_; ++l)
    if (l < il) s += src[((size_t)c * L_ + l) * E_ + ee];
  cat_mean[idx] = s / (float)il;
}

// ---------------- hist LSTM: one step, gates fused ----------------
// grid 64 blocks x 64 threads; thread -> (b, e), computes all 4 gate dots.
__global__ __launch_bounds__(64) void k_hist_step(
    const float* __restrict__ xproj, const float* __restrict__ Whh,
    float* __restrict__ hall, float* __restrict__ c_st, int u) {
  __shared__ float hs[B_ * D_];
  int tid = threadIdx.x;
  for (int i = tid; i < B_ * D_; i += 64) {
    int bb = i >> 9, ee = i & 511;
    hs[i] = (u == 0) ? 0.f : hall[((size_t)bb * U_ + (u - 1)) * D_ + ee];
  }
  __syncthreads();
  int g = blockIdx.x * 64 + tid;
  int b = g >> 9, e = g & 511;
  const float* xp = xproj + ((size_t)b * U_ + u) * D4_;
  float zi = xp[e], zf = xp[e + D_], zg = xp[e + 2 * D_], zo = xp[e + 3 * D_];
  const float4* w0 = (const float4*)(Whh + (size_t)e * D_);
  const float4* w1 = (const float4*)(Whh + (size_t)(e + D_) * D_);
  const float4* w2 = (const float4*)(Whh + (size_t)(e + 2 * D_) * D_);
  const float4* w3 = (const float4*)(Whh + (size_t)(e + 3 * D_) * D_);
  const float4* hv = (const float4*)(hs + (size_t)b * D_);
#pragma unroll 4
  for (int k = 0; k < D_ / 4; ++k) {
    float4 h4 = hv[k];
    float4 a = w0[k]; zi += a.x * h4.x + a.y * h4.y + a.z * h4.z + a.w * h4.w;
    float4 bb4 = w1[k]; zf += bb4.x * h4.x + bb4.y * h4.y + bb4.z * h4.z + bb4.w * h4.w;
    float4 cc4 = w2[k]; zg += cc4.x * h4.x + cc4.y * h4.y + cc4.z * h4.z + cc4.w * h4.w;
    float4 dd4 = w3[k]; zo += dd4.x * h4.x + dd4.y * h4.y + dd4.z * h4.z + dd4.w * h4.w;
  }
  float ig = 1.f / (1.f + expf(-zi));
  float fg = 1.f / (1.f + expf(-zf));
  float gg = tanhf(zg);
  float og = 1.f / (1.f + expf(-zo));
  float cn = fg * c_st[g] + ig * gg;
  c_st[g] = cn;
  hall[((size_t)b * U_ + u) * D_ + e] = og * tanhf(cn);
}

// ---------------- phase A: softmax stats + logit/prob ----------------
// grid = B*T blocks, 256 threads (4 waves = 4 heads)
__global__ __launch_bounds__(256) void k_softmax(
    const float* __restrict__ Sm, const float* __restrict__ Sh,
    float2* __restrict__ stats, float* __restrict__ logit, float* __restrict__ prob) {
  __shared__ float sm[H_][1008];
  __shared__ float ss[H_][1008];
  __shared__ float smx[H_], sinv[H_];
  int bt = blockIdx.x;
  int b = bt / T_;
  int tid = threadIdx.x;
  for (int i = tid; i < H_ * C_; i += 256) sm[i / C_][i % C_] = Sm[(size_t)bt * HC_ + i];
  __syncthreads();
  int wave = tid >> 6, lane = tid & 63;
  for (int u = 0; u < U_; ++u) {
    const float* shrow = Sh + ((size_t)(b * U_ + u) * H_ + wave) * C_;
    float mx = -1e30f;
    for (int c = lane; c < C_; c += 64) {
      float s = sm[wave][c] + shrow[c];
      ss[wave][c] = s;
      mx = fmaxf(mx, s);
    }
#pragma unroll
    for (int o = 32; o; o >>= 1) mx = fmaxf(mx, __shfl_xor(mx, o));
    float sum = 0.f;
    for (int c = lane; c < C_; c += 64) sum += expf(ss[wave][c] - mx);
#pragma unroll
    for (int o = 32; o; o >>= 1) sum += __shfl_xor(sum, o);
    float inv = 1.f / sum;
    if (lane == 0) {
      smx[wave] = mx; sinv[wave] = inv;
      stats[((size_t)bt * U_ + u) * H_ + wave] = make_float2(mx, inv);
    }
    __syncthreads();
    size_t base = ((size_t)bt * U_ + u) * C_;
    for (int c = tid; c < C_; c += 256) {
      float lsum = 0.f, psum = 0.f;
#pragma unroll
      for (int h = 0; h < H_; ++h) {
        float s = ss[h][c];
        lsum += s;
        psum += expf(s - smx[h]) * sinv[h];
      }
      logit[base + c] = lsum * 0.25f;
      prob[base + c] = psum * 0.25f;
    }
    __syncthreads();
  }
}

// ---------------- phase B: PV GEMM with on-the-fly attn ----------------
// grid (TU/64, H, B), 256 threads; 64 rows x 128 cols per block
__global__ __launch_bounds__(256) void k_pv(
    const float* __restrict__ Sm, const float* __restrict__ Sh,
    const float2* __restrict__ stats, const float* __restrict__ v,
    float* __restrict__ attn_out) {
  constexpr int KC = 32;
  __shared__ float As[KC][68];
  __shared__ float Vs[KC][132];
  __shared__ float sSm[4][KC];
  __shared__ float sSh[16][KC];
  __shared__ float2 sst[64];
  int b = blockIdx.z, h = blockIdx.y, tile = blockIdx.x;
  int q0 = tile * 64;
  int t0 = q0 >> 4;
  int tid = threadIdx.x;
  if (tid < 64) {
    int q = q0 + tid;
    int t = q >> 4, u = q & 15;
    sst[tid] = stats[(((size_t)b * T_ + t) * U_ + u) * H_ + h];
  }
  float acc[4][8] = {};
  int tx = tid & 15, ty = tid >> 4;
  for (int c0 = 0; c0 < C_; c0 += KC) {
    for (int i = tid; i < 4 * KC; i += 256) {
      int tt = i / KC, cc = i % KC; int c = c0 + cc;
      sSm[tt][cc] = (c < C_) ? Sm[(((size_t)b * T_ + (t0 + tt)) * H_ + h) * C_ + c] : -1e30f;
    }
    for (int i = tid; i < 16 * KC; i += 256) {
      int uu = i / KC, cc = i % KC; int c = c0 + cc;
      sSh[uu][cc] = (c < C_) ? Sh[(((size_t)b * U_ + uu) * H_ + h) * C_ + c] : -1e30f;
    }
    for (int i = tid; i < KC * 128; i += 256) {
      int cc = i >> 7, dd = i & 127; int c = c0 + cc;
      Vs[cc][dd] = (c < C_) ? v[(size_t)c * D_ + h * 128 + dd] : 0.f;
    }
    __syncthreads();
    for (int i = tid; i < 64 * KC; i += 256) {
      int qq = i / KC, cc = i % KC;
      float2 st = sst[qq];
      float s = sSm[qq >> 4][cc] + sSh[qq & 15][cc];
      As[cc][qq] = expf(s - st.x) * st.y;
    }
    __syncthreads();
#pragma unroll
    for (int k = 0; k < KC; ++k) {
      const float4 a = *(const float4*)&As[k][ty * 4];
      const float4 w0 = *(const float4*)&Vs[k][tx * 8];
      const float4 w1 = *(const float4*)&Vs[k][tx * 8 + 4];
      acc[0][0] += a.x * w0.x; acc[0][1] += a.x * w0.y; acc[0][2] += a.x * w0.z; acc[0][3] += a.x * w0.w;
      acc[0][4] += a.x * w1.x; acc[0][5] += a.x * w1.y; acc[0][6] += a.x * w1.z; acc[0][7] += a.x * w1.w;
      acc[1][0] += a.y * w0.x; acc[1][1] += a.y * w0.y; acc[1][2] += a.y * w0.z; acc[1][3] += a.y * w0.w;
      acc[1][4] += a.y * w1.x; acc[1][5] += a.y * w1.y; acc[1][6] += a.y * w1.z; acc[1][7] += a.y * w1.w;
      acc[2][0] += a.z * w0.x; acc[2][1] += a.z * w0.y; acc[2][2] += a.z * w0.z; acc[2][3] += a.z * w0.w;
      acc[2][4] += a.z * w1.x; acc[2][5] += a.z * w1.y; acc[2][6] += a.z * w1.z; acc[2][7] += a.z * w1.w;
      acc[3][0] += a.w * w0.x; acc[3][1] += a.w * w0.y; acc[3][2] += a.w * w0.z; acc[3][3] += a.w * w0.w;
      acc[3][4] += a.w * w1.x; acc[3][5] += a.w * w1.y; acc[3][6] += a.w * w1.z; acc[3][7] += a.w * w1.w;
    }
    __syncthreads();
  }
#pragma unroll
  for (int i = 0; i < 4; ++i) {
    int q = q0 + ty * 4 + i;
#pragma unroll
    for (int j = 0; j < 8; ++j) {
      attn_out[((size_t)b * TU_ + q) * D_ + h * 128 + tx * 8 + j] = acc[i][j];
    }
  }
}

// ---------------- decode scan helpers ----------------
__global__ __launch_bounds__(256) void k_bits(
    const float* __restrict__ prob, const int* __restrict__ hidx,
    unsigned char* __restrict__ bits) {
  int i = blockIdx.x * 256 + threadIdx.x;
  if (i >= B_ * T_ * U_) return;
  int u = i & 15, bt = i >> 4, b = bt >> 7;
  int valid = (u + 1 < U_ - 1) ? (u + 1) : (U_ - 1);
  int tok = hidx[b * U_ + valid];
  size_t base = (size_t)i * C_;
  bits[i] = (prob[base + tok] > prob[base]) ? 1 : 0;
}

__global__ __launch_bounds__(64) void k_scan(
    const unsigned char* __restrict__ bits, int* __restrict__ u_sel) {
  __shared__ unsigned char sb[B_ * T_ * U_];
  int tid = threadIdx.x;
  for (int i = tid; i < B_ * T_ * U_; i += 64) sb[i] = bits[i];
  __syncthreads();
  if (tid < B_) {
    int u = 0;
    for (int t = 0; t < T_; ++t) {
      int uc = (u < U_ - 1) ? u : (U_ - 1);
      u_sel[tid * T_ + t] = uc;
      u = uc + (int)sb[(tid * T_ + t) * U_ + uc];
    }
  }
}

__global__ __launch_bounds__(128) void k_gather_o(
    const float* __restrict__ out_final, const int* __restrict__ u_sel,
    float* __restrict__ o) {
  int bt = blockIdx.x;
  int uc = u_sel[bt];
  const float4* src = (const float4*)(out_final + ((size_t)bt * U_ + uc) * D_);
  float4* dst = (float4*)(o + (size_t)bt * D_);
  dst[threadIdx.x] = src[threadIdx.x];
}

// ---------------- host launch ----------------
extern "C" void kernel_launch(void* const* d_in, const int* in_sizes, int n_in,
                              void* d_out, int out_size, void* d_ws, size_t ws_size,
                              hipStream_t stream) {
  const float* model_embed = (const float*)d_in[0];
  const float* emb_table   = (const float*)d_in[1];
  const float* Wih_f = (const float*)d_in[2];
  const float* Whh_f = (const float*)d_in[3];
  const float* b_f   = (const float*)d_in[4];
  const float* Wih_b = (const float*)d_in[5];
  const float* Whh_b = (const float*)d_in[6];
  const float* b_b   = (const float*)d_in[7];
  const float* ctx_out_W  = (const float*)d_in[8];
  const float* hist_Wih   = (const float*)d_in[9];
  const float* hist_Whh   = (const float*)d_in[10];
  const float* hist_b     = (const float*)d_in[11];
  const float* hist_out_W = (const float*)d_in[12];
  const float* Wq = (const float*)d_in[13];
  const float* Wk = (const float*)d_in[14];
  const float* Wv = (const float*)d_in[15];
  const float* Wo = (const float*)d_in[16];
  const float* acoustic_W = (const float*)d_in[17];
  const int* ctx_idxs = (const int*)d_in[18];
  const int* hidx     = (const int*)d_in[19];
  const int* ilens    = (const int*)d_in[20];

  if (ws_size < WS_NEED * sizeof(float)) return;  // fail loudly (poison stays)

  float* ws = (float*)d_ws;
  float* o_out     = (float*)d_out;
  float* logit_out = o_out + (size_t)B_ * T_ * D_;
  float* prob_out  = logit_out + (size_t)B_ * T_ * U_ * C_;

  float* zf = ws + Z_CTX;
  float* zb = ws + Z_CTX + (size_t)C_ * E4_;

  // zero LSTM states
  hipMemsetAsync(ws + H_F, 0, 4ul * C_ * E_ * sizeof(float), stream);       // h_f,c_f,h_b,c_b
  hipMemsetAsync(ws + HIST_C, 0, (size_t)B_ * D_ * sizeof(float), stream);  // hist c

  // ---- ctx bi-LSTM: 8 steps, fwd+bwd fused via grid.z ----
  for (int t = 0; t < L_; ++t) {
    GemmP pf{};
    pf.A1 = emb_table; pf.lda1 = E_;
    pf.ridx = ctx_idxs; pf.ridx_stride = L_; pf.ridx_off = t;
    pf.A2 = ws + H_F; pf.lda2 = E_;
    pf.K1 = E_; pf.K2 = E_;
    pf.W1 = Wih_f; pf.ldw1 = E_; pf.W2 = Whh_f; pf.ldw2 = E_;
    pf.bias = b_f; pf.out = zf; pf.ldc = E4_; pf.M = C_; pf.N = E4_; pf.scale = 1.f;
    GemmP pb = pf;
    pb.ridx_off = L_ - 1 - t; pb.A2 = ws + H_Bo;
    pb.W1 = Wih_b; pb.W2 = Whh_b; pb.bias = b_b; pb.out = zb;
    k_gemm2<<<dim3(16, 16, 2), 256, 0, stream>>>(pf, pb);
    k_ctx_gates<<<dim3((C_ * E_ + 255) / 256, 2), 256, 0, stream>>>(
        ws + Z_CTX, ws + H_F, ws + C_F, ws + H_Bo, ws + C_Bo,
        ws + HF_ALL, ws + HB_ALL, t);
  }

  // ---- masked mean, then ctx_out projection ----
  k_ctx_mean<<<dim3((C_ * 2 * E_ + 255) / 256), 256, 0, stream>>>(
      ws + HF_ALL, ws + HB_ALL, ilens, ws + CATM);
  {
    GemmP p{};
    p.A1 = ws + CATM; p.lda1 = 2 * E_; p.K1 = 2 * E_;
    p.W1 = ctx_out_W; p.ldw1 = 2 * E_;
    p.out = ws + CTXM; p.ldc = D_; p.M = C_; p.N = D_; p.scale = 1.f;
    k_gemm<<<dim3(8, 16, 1), 256, 0, stream>>>(p);
  }

  // ---- k (scaled) and v ----
  {
    GemmP pk{};
    pk.A1 = ws + CTXM; pk.lda1 = D_; pk.K1 = D_;
    pk.W1 = Wk; pk.ldw1 = D_;
    pk.out = ws + K_WS; pk.ldc = D_; pk.M = C_; pk.N = D_; pk.scale = SCALE_;
    GemmP pv = pk;
    pv.W1 = Wv; pv.out = ws + V_WS; pv.scale = 1.f;
    k_gemm2<<<dim3(8, 16, 2), 256, 0, stream>>>(pk, pv);
  }

  // ---- hist LSTM input projection (gathered rows) ----
  {
    GemmP p{};
    p.A1 = ws + CTXM; p.lda1 = D_;
    p.ridx = hidx; p.ridx_stride = 1; p.ridx_off = 0;
    p.K1 = D_;
    p.W1 = hist_Wih; p.ldw1 = D_;
    p.bias = hist_b;
    p.out = ws + HXP; p.ldc = D4_; p.M = B_ * U_; p.N = D4_; p.scale = 1.f;
    k_gemm<<<dim3(32, 2, 1), 256, 0, stream>>>(p);
  }

  // ---- hist LSTM recurrence: 16 fused steps ----
  for (int u = 0; u < U_; ++u) {
    k_hist_step<<<dim3(64), 64, 0, stream>>>(ws + HXP, hist_Whh, ws + HALL, ws + HIST_C, u);
  }

  // ---- hist_out, mp, qm, qh ----
  {
    GemmP p{};
    p.A1 = ws + HALL; p.lda1 = D_; p.K1 = D_;
    p.W1 = hist_out_W; p.ldw1 = D_;
    p.out = ws + HPROJ; p.ldc = D_; p.M = B_ * U_; p.N = D_; p.scale = 1.f;
    k_gemm<<<dim3(8, 2, 1), 256, 0, stream>>>(p);
  }
  {
    GemmP p{};
    p.A1 = model_embed; p.lda1 = D_; p.K1 = D_;
    p.W1 = acoustic_W; p.ldw1 = D_;
    p.out = ws + MP_; p.ldc = D_; p.M = B_ * T_; p.N = D_; p.scale = 1.f;
    k_gemm<<<dim3(8, 16, 1), 256, 0, stream>>>(p);
  }
  {
    GemmP p{};
    p.A1 = ws + MP_; p.lda1 = D_; p.K1 = D_;
    p.W1 = Wq; p.ldw1 = D_;
    p.out = ws + QM_; p.ldc = D_; p.M = B_ * T_; p.N = D_; p.scale = 1.f;
    k_gemm<<<dim3(8, 16, 1), 256, 0, stream>>>(p);
  }
  {
    GemmP p{};
    p.A1 = ws + HPROJ; p.lda1 = D_; p.K1 = D_;
    p.W1 = Wq; p.ldw1 = D_;
    p.out = ws + QH_; p.ldc = D_; p.M = B_ * U_; p.N = D_; p.scale = 1.f;
    k_gemm<<<dim3(8, 2, 1), 256, 0, stream>>>(p);
  }

  // ---- Sm, Sh (per-head GEMMs via grid.z) ----
  {
    GemmP p{};
    p.A1 = ws + QM_; p.lda1 = D_; p.K1 = DH_;
    p.W1 = ws + K_WS; p.ldw1 = D_;
    p.out = ws + SM_; p.ldc = HC_; p.M = B_ * T_; p.N = C_; p.scale = 1.f;
    p.a_zoff = DH_; p.w_zoff = DH_; p.c_zoff = C_;
    k_gemm<<<dim3(16, 16, H_), 256, 0, stream>>>(p);
  }
  {
    GemmP p{};
    p.A1 = ws + QH_; p.lda1 = D_; p.K1 = DH_;
    p.W1 = ws + K_WS; p.ldw1 = D_;
    p.out = ws + SH_; p.ldc = HC_; p.M = B_ * U_; p.N = C_; p.scale = 1.f;
    p.a_zoff = DH_; p.w_zoff = DH_; p.c_zoff = C_;
    k_gemm<<<dim3(16, 2, H_), 256, 0, stream>>>(p);
  }

  // ---- softmax stats + logit/prob ----
  k_softmax<<<dim3(B_ * T_), 256, 0, stream>>>(
      ws + SM_, ws + SH_, (float2*)(ws + STATS_), logit_out, prob_out);

  // ---- PV ----
  k_pv<<<dim3(TU_ / 64, H_, B_), 256, 0, stream>>>(
      ws + SM_, ws + SH_, (const float2*)(ws + STATS_), ws + V_WS, ws + AOUT_);

  // ---- Wo projection ----
  {
    GemmP p{};
    p.A1 = ws + AOUT_; p.lda1 = D_; p.K1 = D_;
    p.W1 = Wo; p.ldw1 = D_;
    p.out = ws + OFIN_; p.ldc = D_; p.M = B_ * TU_; p.N = D_; p.scale = 1.f;
    k_gemm<<<dim3(8, 256, 1), 256, 0, stream>>>(p);
  }

  // ---- decode scan + gather o ----
  k_bits<<<dim3(64), 256, 0, stream>>>(prob_out, hidx, (unsigned char*)(ws + BITS_));
  k_scan<<<dim3(1), 64, 0, stream>>>((const unsigned char*)(ws + BITS_), (int*)(ws + USEL_));
  k_gather_o<<<dim3(B_ * T_), 128, 0, stream>>>(ws + OFIN_, (const int*)(ws + USEL_), o_out);
}